// Round 1
// baseline (191.657 us; speedup 1.0000x reference)
//
#include <hip/hip_runtime.h>
#include <hip/hip_cooperative_groups.h>
#include <math.h>

namespace cg = cooperative_groups;

#define SDIM 64
#define BDIM 4
#define NBLK (BDIM * SDIM)   // 256 blocks, one per (b,h)
#define SLICE (SDIM * SDIM)  // 4096
#define TOT (BDIM * SDIM * SDIM) // 16384

// One block per (b,h). 256 threads = 4 waves; wave w owns m in [16w,16w+16),
// lane l owns k=l. All masks are computed on the fly from one edge_mask row:
//   sib_mask[b,h,m,k] = em[b,h,m] & em[b,h,k] & (h!=k)
//   maskEB  [b,h,m,k] = em[b,h,m] & em[b,h,k] & (h!=m)   (swapaxes of sib)
//   mask2o  [b,h,m,k] = sib_mask & (m!=k)
// Iteration update needs q_b/q_e for the WHOLE batch slice (the 'bkm' einsum),
// so each block stages sigmoid(base[b,:,:]) into LDS, and iterations are
// separated by grid.sync() with ping-pong buffers (no read/write aliasing).
__global__ __launch_bounds__(256, 1)
void mfvi_kernel(const float* __restrict__ arg_b, const float* __restrict__ arg_e,
                 const float* __restrict__ t_be, const float* __restrict__ t_eb,
                 const float* __restrict__ t_bb, const float* __restrict__ t_ee,
                 const float* __restrict__ t_cb, const float* __restrict__ t_ce,
                 const void* __restrict__ emp,
                 float* __restrict__ out, float* __restrict__ ws0)
{
    __shared__ float qb[SDIM][SDIM + 1];  // +1 pad: q[k][m] column reads conflict-free
    __shared__ float qe[SDIM][SDIM + 1];
    __shared__ float sum_b[SDIM];
    __shared__ float sum_e[SDIM];
    __shared__ float em_row[SDIM];

    const int bid  = blockIdx.x;
    const int b    = bid >> 6;
    const int h    = bid & 63;
    const int tid  = threadIdx.x;
    const int wave = tid >> 6;
    const int lane = tid & 63;

    // edge_mask representation detection: lens >= S/2 so elements 0..3 are all
    // true -> first 4 bytes disambiguate u8 / i32 / f32 storage.
    const unsigned w0 = *(const unsigned*)emp;
    if (tid < SDIM) {
        const int idx = (b * SDIM + h) * SDIM + tid;
        float v;
        if (w0 == 0x01010101u)      v = ((const unsigned char*)emp)[idx] ? 1.0f : 0.0f;
        else if (w0 == 0x3F800000u) v = (((const float*)emp)[idx] != 0.0f) ? 1.0f : 0.0f;
        else                        v = ((const int*)emp)[idx] ? 1.0f : 0.0f;
        em_row[tid] = v;
    }

    const long base4  = (long)bid * SLICE; // [b][h][0][0] in the 4D tensors
    const int  rowoff = bid * SDIM;        // [b][h][0] in the 3D arrays

    cg::grid_group grid = cg::this_grid();

    for (int it = 0; it < 3; ++it) {
        // ping-pong: arg->out, out->ws, ws->out  (final lands in d_out)
        const float *sb, *se;
        float *db, *de;
        if (it == 0)      { sb = arg_b; se = arg_e;     db = out; de = out + TOT; }
        else if (it == 1) { sb = out;   se = out + TOT; db = ws0; de = ws0 + TOT; }
        else              { sb = ws0;   se = ws0 + TOT; db = out; de = out + TOT; }

        // Stage sigmoid(base[b,:,:]) for the whole batch slice (coalesced).
        for (int i = tid; i < SLICE; i += 256) {
            const float xb = sb[b * SLICE + i];
            const float xe = se[b * SLICE + i];
            qb[i >> 6][i & 63] = 1.0f / (1.0f + expf(-xb));
            qe[i >> 6][i & 63] = 1.0f / (1.0f + expf(-xe));
        }
        __syncthreads();

        const float qbr = qb[h][lane];   // q_b[b,h,k], k = lane
        const float qer = qe[h][lane];   // q_e[b,h,k]
        const float eml = em_row[lane];
        const bool  hnl = (h != lane);

        for (int mi = 0; mi < 16; ++mi) {
            const int   m   = wave * 16 + mi;
            const float c1  = em_row[m] * eml;          // em[b,h,m] & em[b,h,k]
            const float mBE = hnl ? c1 : 0.0f;          // & (h != k)
            const float mEB = (h != m) ? c1 : 0.0f;     // & (h != m)
            const float m2  = (m != lane) ? mBE : 0.0f; // & (m != k)
            const long  off = base4 + (long)m * SDIM + lane; // coalesced: lane=k

            float pb = mBE * t_be[off] * qer
                     + m2  * (t_bb[off] * qbr + t_cb[off] * qb[lane][m]);
            float pe = mEB * t_eb[off] * qbr
                     + m2  * (t_ee[off] * qer + t_ce[off] * qe[lane][m]);

            #pragma unroll
            for (int sft = 32; sft > 0; sft >>= 1) {  // 64-lane butterfly
                pb += __shfl_xor(pb, sft, 64);
                pe += __shfl_xor(pe, sft, 64);
            }
            if (lane == 0) { sum_b[m] = pb; sum_e[m] = pe; }
        }
        __syncthreads();

        if (tid < 128) { // coalesced final add+store of this block's row
            const int m   = tid & 63;
            const int idx = rowoff + m;
            if (tid < 64) db[idx] = sb[idx] + sum_b[m];
            else          de[idx] = se[idx] + sum_e[m];
        }

        if (it < 2) grid.sync();
    }
}

extern "C" void kernel_launch(void* const* d_in, const int* in_sizes, int n_in,
                              void* d_out, int out_size, void* d_ws, size_t ws_size,
                              hipStream_t stream)
{
    const float* arg_b = (const float*)d_in[0];
    const float* arg_e = (const float*)d_in[1];
    const float* t_be  = (const float*)d_in[2];
    const float* t_eb  = (const float*)d_in[3];
    const float* t_bb  = (const float*)d_in[4];
    const float* t_ee  = (const float*)d_in[5];
    const float* t_cb  = (const float*)d_in[6];
    const float* t_ce  = (const float*)d_in[7];
    const void*  emp   = d_in[8];
    float* out = (float*)d_out;
    float* ws0 = (float*)d_ws;   // one intermediate base buffer: 2*TOT floats = 128 KiB

    void* args[] = { (void*)&arg_b, (void*)&arg_e, (void*)&t_be, (void*)&t_eb,
                     (void*)&t_bb, (void*)&t_ee, (void*)&t_cb, (void*)&t_ce,
                     (void*)&emp, (void*)&out, (void*)&ws0 };
    hipLaunchCooperativeKernel((void*)mfvi_kernel, dim3(NBLK), dim3(256),
                               args, 0, stream);
}

// Round 2
// 172.608 us; speedup vs baseline: 1.1104x; 1.1104x over previous
//
#include <hip/hip_runtime.h>
#include <hip/hip_cooperative_groups.h>
#include <math.h>

namespace cg = cooperative_groups;

#define SDIM 64
#define BDIM 4
#define NBLK (BDIM * SDIM)       // 256 blocks, one per (b,h), 1/CU
#define NTHR 1024                // 16 waves/block = 4 waves/SIMD
#define SLICE (SDIM * SDIM)      // 4096
#define TOT (BDIM * SDIM * SDIM) // 16384

// One block per (b,h), 1024 threads = 16 waves; wave w owns m in {4w..4w+3},
// lane l owns k=l. Masks computed on the fly from one edge_mask row:
//   maskBE[m,k] = em[m] & em[k] & (h!=k)
//   maskEB[m,k] = em[m] & em[k] & (h!=m)    (swapaxes of sib_mask)
//   mask2o[m,k] = maskBE & (m!=k)
// All 24 tensor loads per wave are issued before use (MLP); the 8 butterflies
// are interleaved for ILP. grid.sync() between iterations (the 'bkm' einsum
// couples blocks); ping-pong out<->ws so reads never alias writes.
__global__ __launch_bounds__(NTHR, 4)
void mfvi_kernel(const float* __restrict__ arg_b, const float* __restrict__ arg_e,
                 const float* __restrict__ t_be, const float* __restrict__ t_eb,
                 const float* __restrict__ t_bb, const float* __restrict__ t_ee,
                 const float* __restrict__ t_cb, const float* __restrict__ t_ce,
                 const void* __restrict__ emp,
                 float* __restrict__ out, float* __restrict__ ws0)
{
    __shared__ float qb[SDIM][SDIM + 1];  // +1 pad: qb[lane][m] is 2-way (free)
    __shared__ float qe[SDIM][SDIM + 1];
    __shared__ float sum_b[SDIM];
    __shared__ float sum_e[SDIM];
    __shared__ float em_row[SDIM];

    const int bid  = blockIdx.x;
    const int b    = bid >> 6;
    const int h    = bid & 63;
    const int tid  = threadIdx.x;
    const int wave = tid >> 6;     // 0..15
    const int lane = tid & 63;     // k

    // edge_mask representation detection: lens >= S/2 so elements 0..3 are all
    // true -> first 4 bytes disambiguate u8 / i32 / f32 storage.
    const unsigned w0 = *(const unsigned*)emp;
    if (tid < SDIM) {
        const int idx = (b * SDIM + h) * SDIM + tid;
        float v;
        if (w0 == 0x01010101u)      v = ((const unsigned char*)emp)[idx] ? 1.0f : 0.0f;
        else if (w0 == 0x3F800000u) v = (((const float*)emp)[idx] != 0.0f) ? 1.0f : 0.0f;
        else                        v = ((const int*)emp)[idx] ? 1.0f : 0.0f;
        em_row[idx & 63] = v;
    }

    const long base4  = (long)bid * SLICE; // [b][h][0][0] in the 4D tensors
    const int  rowoff = bid * SDIM;        // [b][h][0] in the 3D arrays

    cg::grid_group grid = cg::this_grid();

    for (int it = 0; it < 3; ++it) {
        // ping-pong: arg->out, out->ws, ws->out  (final lands in d_out)
        const float *sb, *se;
        float *db, *de;
        if (it == 0)      { sb = arg_b; se = arg_e;     db = out; de = out + TOT; }
        else if (it == 1) { sb = out;   se = out + TOT; db = ws0; de = ws0 + TOT; }
        else              { sb = ws0;   se = ws0 + TOT; db = out; de = out + TOT; }

        // Stage sigmoid(base[b,:,:]) for the whole batch slice (coalesced).
        #pragma unroll
        for (int r = 0; r < SLICE / NTHR; ++r) {
            const int i = tid + r * NTHR;
            const float xb = sb[b * SLICE + i];
            const float xe = se[b * SLICE + i];
            qb[i >> 6][i & 63] = 1.0f / (1.0f + expf(-xb));
            qe[i >> 6][i & 63] = 1.0f / (1.0f + expf(-xe));
        }
        __syncthreads();

        const float qbr = qb[h][lane];   // q_b[b,h,k], k = lane
        const float qer = qe[h][lane];   // q_e[b,h,k]
        const float eml = em_row[lane];
        const float mhk = (h != lane) ? eml : 0.0f;  // em[k] & (h!=k)

        // ---- issue ALL 24 loads first (4 m's x 6 tensors), then compute ----
        float vbe[4], veb[4], vbb[4], vee[4], vcb[4], vce[4];
        #pragma unroll
        for (int j = 0; j < 4; ++j) {
            const long off = base4 + (long)(wave * 4 + j) * SDIM + lane;
            vbe[j] = t_be[off];
            veb[j] = t_eb[off];
            vbb[j] = t_bb[off];
            vee[j] = t_ee[off];
            vcb[j] = t_cb[off];
            vce[j] = t_ce[off];
        }

        float pb[4], pe[4];
        #pragma unroll
        for (int j = 0; j < 4; ++j) {
            const int   m   = wave * 4 + j;
            const float emm = em_row[m];
            const float mBE = emm * mhk;                       // em[m]&em[k]&(h!=k)
            const float mEB = (h != m) ? emm * eml : 0.0f;     // em[m]&em[k]&(h!=m)
            const float m2  = (m != lane) ? mBE : 0.0f;        // & (m!=k)
            pb[j] = mBE * vbe[j] * qer
                  + m2  * (vbb[j] * qbr + vcb[j] * qb[lane][m]);
            pe[j] = mEB * veb[j] * qbr
                  + m2  * (vee[j] * qer + vce[j] * qe[lane][m]);
        }

        // 8 independent 64-lane butterflies, interleaved for ILP.
        #pragma unroll
        for (int sft = 32; sft > 0; sft >>= 1) {
            #pragma unroll
            for (int j = 0; j < 4; ++j) {
                pb[j] += __shfl_xor(pb[j], sft, 64);
                pe[j] += __shfl_xor(pe[j], sft, 64);
            }
        }
        if (lane == 0) {
            #pragma unroll
            for (int j = 0; j < 4; ++j) {
                sum_b[wave * 4 + j] = pb[j];
                sum_e[wave * 4 + j] = pe[j];
            }
        }
        __syncthreads();

        if (tid < 2 * SDIM) { // coalesced final add+store of this block's row
            const int m   = tid & 63;
            const int idx = rowoff + m;
            if (tid < SDIM) db[idx] = sb[idx] + sum_b[m];
            else            de[idx] = se[idx] + sum_e[m];
        }

        if (it < 2) grid.sync();
    }
}

extern "C" void kernel_launch(void* const* d_in, const int* in_sizes, int n_in,
                              void* d_out, int out_size, void* d_ws, size_t ws_size,
                              hipStream_t stream)
{
    const float* arg_b = (const float*)d_in[0];
    const float* arg_e = (const float*)d_in[1];
    const float* t_be  = (const float*)d_in[2];
    const float* t_eb  = (const float*)d_in[3];
    const float* t_bb  = (const float*)d_in[4];
    const float* t_ee  = (const float*)d_in[5];
    const float* t_cb  = (const float*)d_in[6];
    const float* t_ce  = (const float*)d_in[7];
    const void*  emp   = d_in[8];
    float* out = (float*)d_out;
    float* ws0 = (float*)d_ws;   // one intermediate base buffer: 2*TOT floats = 128 KiB

    void* args[] = { (void*)&arg_b, (void*)&arg_e, (void*)&t_be, (void*)&t_eb,
                     (void*)&t_bb, (void*)&t_ee, (void*)&t_cb, (void*)&t_ce,
                     (void*)&emp, (void*)&out, (void*)&ws0 };
    hipLaunchCooperativeKernel((void*)mfvi_kernel, dim3(NBLK), dim3(NTHR),
                               args, 0, stream);
}

// Round 4
// 104.016 us; speedup vs baseline: 1.8426x; 1.6594x over previous
//
#include <hip/hip_runtime.h>
#include <math.h>

#define SDIM 64
#define SLICE (SDIM * SDIM)      // 4096
#define TOT (4 * SDIM * SDIM)    // 16384

// One MFVI iteration per launch (launch boundary = device-wide barrier,
// replacing grid.sync()). Grid 1024 = B(4) x h(64) x mchunk(4); block 256 =
// 4 waves; wave w owns m in {mc*16 + 4w .. +3}, lane l owns k=l.
// Masks from one edge_mask row, on the fly:
//   maskBE[m,k] = em[m] & em[k] & (h!=k)
//   maskEB[m,k] = em[m] & em[k] & (h!=m)   (swapaxes of sib_mask)
//   mask2o[m,k] = maskBE & (m!=k)
// Each block stages sigmoid of ONLY what it needs: 16 q-columns (for the
// 'bkm' cop einsum) + row h (for the 'bhk' einsums). The 24 tensor loads are
// issued BEFORE staging so HBM latency hides under the sigmoid work.
__global__ __launch_bounds__(256, 4)
void mfvi_iter(const float* __restrict__ sb, const float* __restrict__ se,
               const float* __restrict__ t_be, const float* __restrict__ t_eb,
               const float* __restrict__ t_bb, const float* __restrict__ t_ee,
               const float* __restrict__ t_cb, const float* __restrict__ t_ce,
               const void* __restrict__ emp,
               float* __restrict__ db, float* __restrict__ de)
{
    __shared__ float qcb[SDIM][17];  // q_b[b, k, mc*16+j]; stride 17
    __shared__ float qce[SDIM][17];
    __shared__ float qrb[SDIM], qre[SDIM], em_row[SDIM];
    __shared__ float sum_b[16], sum_e[16];

    const int bid  = blockIdx.x;
    const int mc   = bid & 3;          // fastest: consecutive blocks read contiguous 4KB
    const int h    = (bid >> 2) & 63;
    const int b    = bid >> 8;
    const int tid  = threadIdx.x;
    const int wave = tid >> 6;
    const int lane = tid & 63;

    const long base4 = (long)(b * SDIM + h) * SLICE;

    // ---- issue ALL 24 tensor loads first (no LDS dependence) ----
    float vbe[4], veb[4], vbb[4], vee[4], vcb[4], vce[4];
    #pragma unroll
    for (int jj = 0; jj < 4; ++jj) {
        const int  m   = mc * 16 + wave * 4 + jj;
        const long off = base4 + (long)m * SDIM + lane;  // coalesced: lane=k
        vbe[jj] = t_be[off]; veb[jj] = t_eb[off]; vbb[jj] = t_bb[off];
        vee[jj] = t_ee[off]; vcb[jj] = t_cb[off]; vce[jj] = t_ce[off];
    }

    // ---- stage the 16 q-columns this block consumes: q[b, k, mc*16+j] ----
    #pragma unroll
    for (int r = 0; r < 4; ++r) {
        const int t = tid + r * 256;       // 0..1023
        const int k = t >> 4, j = t & 15;
        const int a = b * SLICE + k * SDIM + mc * 16 + j;
        qcb[k][j] = 1.0f / (1.0f + expf(-sb[a]));
        qce[k][j] = 1.0f / (1.0f + expf(-se[a]));
    }
    if (tid < SDIM) {
        const int a = b * SLICE + h * SDIM + tid;
        qrb[tid] = 1.0f / (1.0f + expf(-sb[a]));
        qre[tid] = 1.0f / (1.0f + expf(-se[a]));
        // edge_mask representation detection: lens >= S/2 so elements 0..3
        // are true -> first 4 bytes disambiguate u8 / i32 / f32 storage.
        const unsigned w0 = *(const unsigned*)emp;
        const int ei = (b * SDIM + h) * SDIM + tid;
        float v;
        if (w0 == 0x01010101u)      v = ((const unsigned char*)emp)[ei] ? 1.0f : 0.0f;
        else if (w0 == 0x3F800000u) v = (((const float*)emp)[ei] != 0.0f) ? 1.0f : 0.0f;
        else                        v = ((const int*)emp)[ei] ? 1.0f : 0.0f;
        em_row[tid] = v;
    }
    __syncthreads();

    const float qbr = qrb[lane];   // q_b[b,h,k], k = lane
    const float qer = qre[lane];
    const float eml = em_row[lane];
    const float mhk = (h != lane) ? eml : 0.0f;      // em[k] & (h!=k)

    float pb[4], pe[4];
    #pragma unroll
    for (int jj = 0; jj < 4; ++jj) {
        const int   j   = wave * 4 + jj;
        const int   m   = mc * 16 + j;
        const float emm = em_row[m];
        const float mBE = emm * mhk;                    // em[m]&em[k]&(h!=k)
        const float mEB = (h != m) ? emm * eml : 0.0f;  // em[m]&em[k]&(h!=m)
        const float m2  = (m != lane) ? mBE : 0.0f;     // & (m!=k)
        pb[jj] = mBE * vbe[jj] * qer
               + m2  * (vbb[jj] * qbr + vcb[jj] * qcb[lane][j]);
        pe[jj] = mEB * veb[jj] * qbr
               + m2  * (vee[jj] * qer + vce[jj] * qce[lane][j]);
    }

    // 8 independent 64-lane butterflies, interleaved for ILP
    #pragma unroll
    for (int sft = 32; sft > 0; sft >>= 1) {
        #pragma unroll
        for (int jj = 0; jj < 4; ++jj) {
            pb[jj] += __shfl_xor(pb[jj], sft, 64);
            pe[jj] += __shfl_xor(pe[jj], sft, 64);
        }
    }
    if (lane == 0) {
        #pragma unroll
        for (int jj = 0; jj < 4; ++jj) {
            sum_b[wave * 4 + jj] = pb[jj];
            sum_e[wave * 4 + jj] = pe[jj];
        }
    }
    __syncthreads();

    if (tid < 32) {
        const int j   = tid & 15;
        const int idx = (b * SDIM + h) * SDIM + mc * 16 + j;
        if (tid < 16) db[idx] = sb[idx] + sum_b[j];
        else          de[idx] = se[idx] + sum_e[j];
    }
}

extern "C" void kernel_launch(void* const* d_in, const int* in_sizes, int n_in,
                              void* d_out, int out_size, void* d_ws, size_t ws_size,
                              hipStream_t stream)
{
    const float* arg_b = (const float*)d_in[0];
    const float* arg_e = (const float*)d_in[1];
    const float* t_be  = (const float*)d_in[2];
    const float* t_eb  = (const float*)d_in[3];
    const float* t_bb  = (const float*)d_in[4];
    const float* t_ee  = (const float*)d_in[5];
    const float* t_cb  = (const float*)d_in[6];
    const float* t_ce  = (const float*)d_in[7];
    const void*  emp   = d_in[8];
    float* out = (float*)d_out;           // [base_b | base_e]
    float* ws  = (float*)d_ws;            // intermediate [base_b | base_e], 128 KiB

    // it0: arg -> out ; it1: out -> ws ; it2: ws -> out
    mfvi_iter<<<1024, 256, 0, stream>>>(arg_b, arg_e, t_be, t_eb, t_bb, t_ee,
                                        t_cb, t_ce, emp, out, out + TOT);
    mfvi_iter<<<1024, 256, 0, stream>>>(out, out + TOT, t_be, t_eb, t_bb, t_ee,
                                        t_cb, t_ce, emp, ws, ws + TOT);
    mfvi_iter<<<1024, 256, 0, stream>>>(ws, ws + TOT, t_be, t_eb, t_bb, t_ee,
                                        t_cb, t_ce, emp, out, out + TOT);
}